// Round 3
// baseline (706.642 us; speedup 1.0000x reference)
//
#include <hip/hip_runtime.h>

// CRF Viterbi decode, B=256, T=512, C=128.
// Outputs (flat f32): viterbi [B,T], inputs copy [B,T,C], seq_len [B], trans copy [C,C].
//
// Value-only forward DP (exact: fp max is order-independent) + backpointer
// RECOMPUTE during backtrack from a stored state history (exact first-max).
// 1024 thr/block, 1 block/batch. Thread (ccur=tid>>3, g=tid&7).

#define BB 256
#define TT 512
#define CC 128
#define NTH 1024
#define GR 8
#define JP 16
#define SPAD 20  // padded dword stride: g*20 mod 32 covers all banks -> conflict-free b128

#define OFF_VIT 0
#define OFF_INP (BB * TT)                 // 131072
#define OFF_LEN (OFF_INP + BB * TT * CC)  // 16908288
#define OFF_TR (OFF_LEN + BB)             // 16908544

#define TRT_FLOATS (CC * CC)          // 64 KB transposed transitions (for backtrack)
#define STATE_FLOATS (2 * GR * SPAD)  // 320
#define SMEM_BYTES ((TRT_FLOATS + STATE_FLOATS + 16) * 4 + 16)

#define F3(a, b, c) fmaxf(fmaxf((a), (b)), (c))

template <int C>
__device__ __forceinline__ float dppmaxf(float v) {
  float o = __int_as_float(__builtin_amdgcn_update_dpp(0, __float_as_int(v), C, 0xF, 0xF, true));
  return fmaxf(v, o);
}

__device__ __forceinline__ void lexmax(float& v, int& i, float ov, int oi) {
  bool take = (ov > v) || (ov == v && oi < i);  // first-max: lowest index wins ties
  v = take ? ov : v;
  i = take ? oi : i;
}
template <int C>
__device__ __forceinline__ void bfly_dpp(float& v, int& i) {
  float ov = __int_as_float(__builtin_amdgcn_update_dpp(0, __float_as_int(v), C, 0xF, 0xF, true));
  int oi = __builtin_amdgcn_update_dpp(0, i, C, 0xF, 0xF, true);
  lexmax(v, i, ov, oi);
}
// full 64-lane lex-argmax reduce (all lanes end with the result)
__device__ __forceinline__ void bfly6(float& v, int& i) {
  bfly_dpp<0xB1>(v, i);   // xor1 (quad_perm [1,0,3,2])
  bfly_dpp<0x4E>(v, i);   // xor2 (quad_perm [2,3,0,1])
  bfly_dpp<0x141>(v, i);  // pair 4-groups (row_half_mirror)
  bfly_dpp<0x140>(v, i);  // pair 8-groups (row_mirror)
  { float ov = __shfl_xor(v, 16); int oi = __shfl_xor(i, 16); lexmax(v, i, ov, oi); }
  { float ov = __shfl_xor(v, 32); int oi = __shfl_xor(i, 32); lexmax(v, i, ov, oi); }
}

__global__ __launch_bounds__(NTH, 1) void crf_viterbi(
    const float* __restrict__ inputs, const unsigned char* __restrict__ mask_bytes,
    const float* __restrict__ trans, float* __restrict__ out,
    float* __restrict__ hist, int useWs) {
  extern __shared__ float smemf[];
  float* trT = smemf;                       // [C][C] transposed transitions
  float* state_s = smemf + TRT_FLOATS;      // [2][GR*SPAD] padded dbuf state
  int* wsum = (int*)(state_s + STATE_FLOATS);

  const int b = blockIdx.x;
  const int tid = threadIdx.x;
  const int lane = tid & 63;
  const int wave = tid >> 6;
  const int ccur = tid >> 3;  // 0..127
  const int g = tid & 7;      // cprev group (8 lanes per tag, aligned)

  // mask dtype detection: int32 (byte1 of elem0 == 0) vs bool/int8
  const int w4 = (mask_bytes[1] == 0) ? 4 : 1;
  if (tid < TT) {
    int mb = mask_bytes[(size_t)(b * TT + tid) * (size_t)w4] != 0;
    unsigned long long bal = __ballot(mb);
    if (lane == 0) wsum[wave] = __popcll(bal);
  }

  // stage transposed transitions into LDS (coalesced global read, scattered LDS write)
  {
    const float4* tsrc = (const float4*)(trans + tid * 16);
    float4 q0 = tsrc[0], q1 = tsrc[1], q2 = tsrc[2], q3 = tsrc[3];
    int p = tid >> 3, c0 = (tid & 7) * 16;
    trT[(c0 + 0) * CC + p] = q0.x;  trT[(c0 + 1) * CC + p] = q0.y;
    trT[(c0 + 2) * CC + p] = q0.z;  trT[(c0 + 3) * CC + p] = q0.w;
    trT[(c0 + 4) * CC + p] = q1.x;  trT[(c0 + 5) * CC + p] = q1.y;
    trT[(c0 + 6) * CC + p] = q1.z;  trT[(c0 + 7) * CC + p] = q1.w;
    trT[(c0 + 8) * CC + p] = q2.x;  trT[(c0 + 9) * CC + p] = q2.y;
    trT[(c0 + 10) * CC + p] = q2.z; trT[(c0 + 11) * CC + p] = q2.w;
    trT[(c0 + 12) * CC + p] = q3.x; trT[(c0 + 13) * CC + p] = q3.y;
    trT[(c0 + 14) * CC + p] = q3.z; trT[(c0 + 15) * CC + p] = q3.w;
  }

  // forward transition fragment in registers: tr[j] = trans[g*16+j][ccur]
  float tr[JP];
#pragma unroll
  for (int j = 0; j < JP; ++j) tr[j] = trans[(g * JP + j) * CC + ccur];

  const float* pin = inputs + (size_t)b * TT * CC;
  float* hist_b = hist + (size_t)b * TT * CC;

  // init: state(0) = inputs[b,0,:], also store hist row 0
  if (tid < CC) {
    float x0 = pin[tid];
    state_s[(tid >> 4) * SPAD + (tid & 15)] = x0;
    hist_b[tid] = x0;
  }
  __syncthreads();

  int L = 0;
#pragma unroll
  for (int i = 0; i < 8; ++i) L += wsum[i];  // L in [256, 512]

  float pot = pin[CC + ccur];  // pot for t=1
  int par = 0;

  // ---- value-only forward DP: one light barrier per step (no vmcnt drain) ----
  for (int t = 1; t < L; ++t) {
    const float4* sp = (const float4*)(state_s + par * (GR * SPAD) + g * SPAD);
    float4 a0 = sp[0], a1 = sp[1], a2 = sp[2], a3 = sp[3];

    int tn = (t + 1 < L) ? (t + 1) : t;
    float potN = pin[tn * CC + ccur];  // prefetch, stays in flight across barrier

    float t0 = a0.x + tr[0], t1 = a0.y + tr[1], t2 = a0.z + tr[2], t3 = a0.w + tr[3];
    float t4 = a1.x + tr[4], t5 = a1.y + tr[5], t6 = a1.z + tr[6], t7 = a1.w + tr[7];
    float t8 = a2.x + tr[8], t9 = a2.y + tr[9], tA = a2.z + tr[10], tB = a2.w + tr[11];
    float tC = a3.x + tr[12], tD = a3.y + tr[13], tE = a3.z + tr[14], tF = a3.w + tr[15];

    // exact max (order-independent), fuses to v_max3
    float m = fmaxf(F3(F3(t0, t1, t2), F3(t3, t4, t5), F3(t6, t7, t8)),
                    F3(F3(t9, tA, tB), F3(tC, tD, tE), tF));
    m = dppmaxf<0xB1>(m);
    m = dppmaxf<0x4E>(m);
    m = dppmaxf<0x141>(m);
    float v = m + pot;

    if (g == 0) {
      state_s[(par ^ 1) * (GR * SPAD) + (ccur >> 4) * SPAD + (ccur & 15)] = v;
      hist_b[t * CC + ccur] = v;  // state history for backtrack recompute
    }
    pot = potN;
    // LDS-only barrier: do NOT drain vmcnt (hist stores + pot loads stay in flight)
    asm volatile("s_waitcnt lgkmcnt(0)\n\ts_barrier" ::: "memory");
    par ^= 1;
  }

  __syncthreads();  // full drain: hist stores visible to wave 0

  float* outv = out + OFF_VIT + b * TT;

  if (wave == 0) {
    // final argmax over state(L-1): 2 values/lane + 64-lane lex butterfly
    const float* fs = state_s + par * (GR * SPAD);
    int p0 = 2 * lane;
    float2 sv = *(const float2*)&fs[(p0 >> 4) * SPAD + (p0 & 15)];
    float v = sv.x;
    int bi = p0;
    if (sv.y > v) { v = sv.y; bi = p0 + 1; }
    bfly6(v, bi);

    for (int t2 = L - 1 + lane; t2 < TT; t2 += 64) outv[t2] = (float)bi;
    if (lane == 0) out[OFF_LEN + b] = (float)L;

    // backtrack: recompute bp along the path; hist rows prefetched depth-3
    // (row addresses are path-independent)
    int cur = bi;
    float2 r0 = *(const float2*)(hist_b + (size_t)(L - 2) * CC + p0);
    float2 r1 = *(const float2*)(hist_b + (size_t)(L >= 3 ? L - 3 : 0) * CC + p0);
    float2 r2 = *(const float2*)(hist_b + (size_t)(L >= 4 ? L - 4 : 0) * CC + p0);
    for (int t = L - 1; t >= 1; --t) {
      float2 w = *(const float2*)&trT[cur * CC + p0];  // trans[p][cur], p=p0,p0+1
      float s0 = r0.x + w.x, s1 = r0.y + w.y;
      float vv = s0;
      int ii = p0;
      if (s1 > vv) { vv = s1; ii = p0 + 1; }
      bfly6(vv, ii);  // exact first-max argmax over 128 cprev
      cur = ii;
      if (lane == 0) outv[t - 1] = (float)cur;
      r0 = r1; r1 = r2;
      int tp = t - 4;
      if (tp < 0) tp = 0;
      r2 = *(const float2*)(hist_b + (size_t)tp * CC + p0);
    }
  }

  // hist-in-out fallback: backtrack must finish reading before copy overwrites
  if (!useWs) __syncthreads();

  if (wave != 0) {
    if (wave == 1) out[OFF_TR + b * 64 + lane] = trans[b * 64 + lane];
    const float4* src = (const float4*)pin;
    float4* dst = (float4*)(out + OFF_INP + (size_t)b * TT * CC);
    for (int i = tid - 64; i < TT * CC / 4; i += NTH - 64) dst[i] = src[i];
  }
}

extern "C" void kernel_launch(void* const* d_in, const int* in_sizes, int n_in,
                              void* d_out, int out_size, void* d_ws, size_t ws_size,
                              hipStream_t stream) {
  const float* inputs = (const float*)d_in[0];
  const unsigned char* mask = (const unsigned char*)d_in[1];
  const float* trans = (const float*)d_in[2];
  float* out = (float*)d_out;

  const size_t need = (size_t)BB * TT * CC * sizeof(float);  // 64 MB state history
  int useWs = (ws_size >= need) ? 1 : 0;
  float* hist = useWs ? (float*)d_ws : (out + OFF_INP);

  crf_viterbi<<<BB, NTH, SMEM_BYTES, stream>>>(inputs, mask, trans, out, hist, useWs);
}

// Round 4
// 440.267 us; speedup vs baseline: 1.6050x; 1.6050x over previous
//
#include <hip/hip_runtime.h>

// CRF Viterbi decode, B=256, T=512, C=128.
// Outputs (flat f32): viterbi [B,T], inputs copy [B,T,C], seq_len [B], trans copy [C,C].
//
// Forward: value-only max (exact, order-independent) + cheap backpointer via
// equality priority-encode + cluster u32-min (exact first-max tie rule).
// Backpointers u8 in LDS; tail backtrack = 511 dependent u8 LDS loads.
// 1024 thr/block, 1 block/batch. Thread (ccur=tid>>3, g=tid&7).

#define BB 256
#define TT 512
#define CC 128
#define NTH 1024
#define GR 8
#define JP 16
#define SPAD 20  // padded dword stride: g*20 mod 32 all-distinct -> conflict-free b128

#define OFF_VIT 0
#define OFF_INP (BB * TT)                 // 131072
#define OFF_LEN (OFF_INP + BB * TT * CC)  // 16908288
#define OFF_TR (OFF_LEN + BB)             // 16908544

#define BP_BYTES ((TT - 1) * CC)      // 65408, 16B aligned
#define STATE_FLOATS (2 * GR * SPAD)  // 320
#define SMEM_BYTES (BP_BYTES + STATE_FLOATS * 4 + 16 * 4 + 16)

#define F3(a, b, c) fmaxf(fmaxf((a), (b)), (c))

template <int C>
__device__ __forceinline__ float dppmaxf(float v) {
  float o = __int_as_float(__builtin_amdgcn_update_dpp(0, __float_as_int(v), C, 0xF, 0xF, true));
  return fmaxf(v, o);
}
template <int C>
__device__ __forceinline__ unsigned dppminu(unsigned v) {
  unsigned o = (unsigned)__builtin_amdgcn_update_dpp(0, (int)v, C, 0xF, 0xF, true);
  return v < o ? v : o;
}

__device__ __forceinline__ void lexmax(float& v, int& i, float ov, int oi) {
  bool take = (ov > v) || (ov == v && oi < i);  // first-max: lowest index wins ties
  v = take ? ov : v;
  i = take ? oi : i;
}
template <int C>
__device__ __forceinline__ void bfly_dpp(float& v, int& i) {
  float ov = __int_as_float(__builtin_amdgcn_update_dpp(0, __float_as_int(v), C, 0xF, 0xF, true));
  int oi = __builtin_amdgcn_update_dpp(0, i, C, 0xF, 0xF, true);
  lexmax(v, i, ov, oi);
}
__device__ __forceinline__ void bfly6(float& v, int& i) {
  bfly_dpp<0xB1>(v, i);   // xor1
  bfly_dpp<0x4E>(v, i);   // xor2
  bfly_dpp<0x141>(v, i);  // row_half_mirror (8)
  bfly_dpp<0x140>(v, i);  // row_mirror (16)
  { float ov = __shfl_xor(v, 16); int oi = __shfl_xor(i, 16); lexmax(v, i, ov, oi); }
  { float ov = __shfl_xor(v, 32); int oi = __shfl_xor(i, 32); lexmax(v, i, ov, oi); }
}

__global__ __launch_bounds__(NTH, 1) void crf_viterbi(
    const float* __restrict__ inputs, const unsigned char* __restrict__ mask_bytes,
    const float* __restrict__ trans, float* __restrict__ out) {
  extern __shared__ unsigned char smem[];
  unsigned char* bp_s = smem;                  // [T-1][C] u8 backpointers
  float* state_s = (float*)(smem + BP_BYTES);  // [2][GR*SPAD] padded dbuf state
  int* wsum = (int*)(state_s + STATE_FLOATS);

  const int b = blockIdx.x;
  const int tid = threadIdx.x;
  const int lane = tid & 63;
  const int wave = tid >> 6;
  const int ccur = tid >> 3;  // 0..127
  const int g = tid & 7;      // cprev group (8 adjacent lanes per tag)
  const bool g0 = (g == 0);

  // mask dtype detection: int32 (byte1 of elem0 == 0) vs bool/int8
  const int w4 = (mask_bytes[1] == 0) ? 4 : 1;
  if (tid < TT) {
    int mb = mask_bytes[(size_t)(b * TT + tid) * (size_t)w4] != 0;
    unsigned long long bal = __ballot(mb);
    if (lane == 0) wsum[wave] = __popcll(bal);
  }

  // forward transition fragment in registers: tr[j] = trans[g*16+j][ccur]
  float tr[JP];
#pragma unroll
  for (int j = 0; j < JP; ++j) tr[j] = trans[(g * JP + j) * CC + ccur];

  const float* pin = inputs + (size_t)b * TT * CC;

  // init: state(0) = inputs[b,0,:]
  if (tid < CC) state_s[(tid >> 4) * SPAD + (tid & 15)] = pin[tid];
  __syncthreads();

  int L = 0;
#pragma unroll
  for (int i = 0; i < 8; ++i) L += wsum[i];  // L in [256, 512]

  float pot = g0 ? pin[CC + ccur] : 0.f;  // pot(t=1), writer lanes only
  int par = 0;

  // ---- forward DP: one light (lgkmcnt-only) barrier per step ----
  for (int t = 1; t < L; ++t) {
    const float4* sp = (const float4*)(state_s + par * (GR * SPAD) + g * SPAD);
    float4 a0 = sp[0], a1 = sp[1], a2 = sp[2], a3 = sp[3];

    int tn = (t + 1 < L) ? (t + 1) : t;
    float potN = 0.f;
    if (g0) potN = pin[tn * CC + ccur];  // prefetch, stays in flight across barrier

    float t0 = a0.x + tr[0], t1 = a0.y + tr[1], t2 = a0.z + tr[2], t3 = a0.w + tr[3];
    float t4 = a1.x + tr[4], t5 = a1.y + tr[5], t6 = a1.z + tr[6], t7 = a1.w + tr[7];
    float t8 = a2.x + tr[8], t9 = a2.y + tr[9], tA = a2.z + tr[10], tB = a2.w + tr[11];
    float tC = a3.x + tr[12], tD = a3.y + tr[13], tE = a3.z + tr[14], tF = a3.w + tr[15];

    // exact max over this lane's 16, then over the 8-lane cluster
    float m = fmaxf(F3(F3(t0, t1, t2), F3(t3, t4, t5), F3(t6, t7, t8)),
                    F3(F3(t9, tA, tB), F3(tC, tD, tE), tF));
    m = dppmaxf<0xB1>(m);
    m = dppmaxf<0x4E>(m);
    m = dppmaxf<0x141>(m);

    // first-index argmax: two parallel reverse cndmask chains (sentinel 255)
    unsigned iA = 255u, iB = 255u;
    iA = (t7 == m) ? 7u : iA;  iB = (tF == m) ? 15u : iB;
    iA = (t6 == m) ? 6u : iA;  iB = (tE == m) ? 14u : iB;
    iA = (t5 == m) ? 5u : iA;  iB = (tD == m) ? 13u : iB;
    iA = (t4 == m) ? 4u : iA;  iB = (tC == m) ? 12u : iB;
    iA = (t3 == m) ? 3u : iA;  iB = (tB == m) ? 11u : iB;
    iA = (t2 == m) ? 2u : iA;  iB = (tA == m) ? 10u : iB;
    iA = (t1 == m) ? 1u : iA;  iB = (t9 == m) ? 9u : iB;
    iA = (t0 == m) ? 0u : iA;  iB = (t8 == m) ? 8u : iB;
    unsigned bi = ((iA != 255u) ? iA : iB) + (unsigned)(g * JP);  // global idx or >=255
    // cluster min over 8 lanes -> smallest global cprev index among equal-to-max
    bi = dppminu<0xB1>(bi);
    bi = dppminu<0x4E>(bi);
    bi = dppminu<0x141>(bi);

    if (g0) {
      state_s[(par ^ 1) * (GR * SPAD) + (ccur >> 4) * SPAD + (ccur & 15)] = m + pot;
      bp_s[(t - 1) * CC + ccur] = (unsigned char)bi;
    }
    pot = potN;
    // LDS-only barrier: no vmcnt drain (pot prefetch stays in flight)
    asm volatile("s_waitcnt lgkmcnt(0)\n\ts_barrier" ::: "memory");
    par ^= 1;
  }

  float* outv = out + OFF_VIT + b * TT;

  // --- epilogue: wave 0 = final argmax + backtrack; waves 1..15 = bulk copies ---
  if (wave == 0) {
    const float* fs = state_s + par * (GR * SPAD);
    float v1 = fs[(lane >> 4) * SPAD + (lane & 15)];
    int c2 = lane + 64;
    float v2 = fs[(c2 >> 4) * SPAD + (c2 & 15)];
    float v;
    int idx;
    if (v2 > v1) { v = v2; idx = c2; } else { v = v1; idx = lane; }
    bfly6(v, idx);

    // tags for t >= L-1 all equal last_tag (identity backpointers past length)
    for (int t2 = L - 1 + lane; t2 < TT; t2 += 64) outv[t2] = (float)idx;
    if (lane == 0) {
      out[OFF_LEN + b] = (float)L;
      int cur = idx;
      for (int tt = L - 2; tt >= 0; --tt) {
        cur = bp_s[tt * CC + cur];
        outv[tt] = (float)cur;
      }
    }
  } else {
    if (wave == 1) out[OFF_TR + b * 64 + lane] = trans[b * 64 + lane];
    const float4* src = (const float4*)pin;
    float4* dst = (float4*)(out + OFF_INP + (size_t)b * TT * CC);
    for (int i = tid - 64; i < TT * CC / 4; i += NTH - 64) dst[i] = src[i];
  }
}

extern "C" void kernel_launch(void* const* d_in, const int* in_sizes, int n_in,
                              void* d_out, int out_size, void* d_ws, size_t ws_size,
                              hipStream_t stream) {
  const float* inputs = (const float*)d_in[0];
  const unsigned char* mask = (const unsigned char*)d_in[1];
  const float* trans = (const float*)d_in[2];
  float* out = (float*)d_out;

  crf_viterbi<<<BB, NTH, SMEM_BYTES, stream>>>(inputs, mask, trans, out);
}

// Round 5
// 410.968 us; speedup vs baseline: 1.7195x; 1.0713x over previous
//
#include <hip/hip_runtime.h>

// CRF Viterbi decode, B=256, T=512, C=128.
// Outputs (flat f32): viterbi [B,T], inputs copy [B,T,C], seq_len [B], trans copy [C,C].
//
// Forward: value-only max (exact, order-independent); backpointer = equality
// priority-encode + cluster u32-min (exact first-max tie rule), SOFTWARE-
// PIPELINED into the next step's LDS-read shadow. Hand-unrolled x2 so the
// double-buffer parity folds into compile-time ds offsets. 2-deep pot prefetch.
// Backpointers u8 in LDS; tail backtrack = dependent u8 LDS loads (wave 0)
// overlapped with bulk copies (waves 1..15).
// 1024 thr/block, 1 block/batch. Thread (ccur=tid>>3, g=tid&7).

#define BB 256
#define TT 512
#define CC 128
#define NTH 1024
#define GR 8
#define JP 16
#define SPAD 20  // padded dword stride: g*20 mod 32 all-distinct -> conflict-free b128

#define OFF_VIT 0
#define OFF_INP (BB * TT)                 // 131072
#define OFF_LEN (OFF_INP + BB * TT * CC)  // 16908288
#define OFF_TR (OFF_LEN + BB)             // 16908544

#define BP_BYTES ((TT - 1) * CC)      // 65408, 16B aligned
#define STATE_FLOATS (2 * GR * SPAD)  // 320
#define SMEM_BYTES (BP_BYTES + STATE_FLOATS * 4 + 16 * 4 + 16)

#define F3(a, b, c) fmaxf(fmaxf((a), (b)), (c))

template <int C>
__device__ __forceinline__ float dppmaxf(float v) {
  float o = __int_as_float(__builtin_amdgcn_update_dpp(0, __float_as_int(v), C, 0xF, 0xF, true));
  return fmaxf(v, o);
}
template <int C>
__device__ __forceinline__ unsigned dppminu(unsigned v) {
  unsigned o = (unsigned)__builtin_amdgcn_update_dpp(0, (int)v, C, 0xF, 0xF, true);
  return v < o ? v : o;
}

__device__ __forceinline__ void lexmax(float& v, int& i, float ov, int oi) {
  bool take = (ov > v) || (ov == v && oi < i);  // first-max: lowest index wins ties
  v = take ? ov : v;
  i = take ? oi : i;
}
template <int C>
__device__ __forceinline__ void bfly_dpp(float& v, int& i) {
  float ov = __int_as_float(__builtin_amdgcn_update_dpp(0, __float_as_int(v), C, 0xF, 0xF, true));
  int oi = __builtin_amdgcn_update_dpp(0, i, C, 0xF, 0xF, true);
  lexmax(v, i, ov, oi);
}
__device__ __forceinline__ void bfly6(float& v, int& i) {
  bfly_dpp<0xB1>(v, i);   // xor1
  bfly_dpp<0x4E>(v, i);   // xor2
  bfly_dpp<0x141>(v, i);  // row_half_mirror (8)
  bfly_dpp<0x140>(v, i);  // row_mirror (16)
  { float ov = __shfl_xor(v, 16); int oi = __shfl_xor(i, 16); lexmax(v, i, ov, oi); }
  { float ov = __shfl_xor(v, 32); int oi = __shfl_xor(i, 32); lexmax(v, i, ov, oi); }
}

// previous step's backpointer: equality encode vs cluster max + 8-lane u32-min
#define DO_BP                                                                  \
  {                                                                            \
    unsigned iA = 255u, iB = 255u;                                             \
    iA = (s7 == sm) ? 7u : iA;  iB = (sF == sm) ? 15u : iB;                    \
    iA = (s6 == sm) ? 6u : iA;  iB = (sE == sm) ? 14u : iB;                    \
    iA = (s5 == sm) ? 5u : iA;  iB = (sD == sm) ? 13u : iB;                    \
    iA = (s4 == sm) ? 4u : iA;  iB = (sC == sm) ? 12u : iB;                    \
    iA = (s3 == sm) ? 3u : iA;  iB = (sB == sm) ? 11u : iB;                    \
    iA = (s2 == sm) ? 2u : iA;  iB = (sA == sm) ? 10u : iB;                    \
    iA = (s1 == sm) ? 1u : iA;  iB = (s9 == sm) ? 9u : iB;                     \
    iA = (s0 == sm) ? 0u : iA;  iB = (s8 == sm) ? 8u : iB;                     \
    unsigned bi = ((iA != 255u) ? iA : iB) + gbase;                            \
    bi = dppminu<0xB1>(bi);                                                    \
    bi = dppminu<0x4E>(bi);                                                    \
    bi = dppminu<0x141>(bi);                                                   \
    if (g0) *bpw = (unsigned char)bi;                                          \
    bpw += CC;                                                                 \
  }

// One DP step. ROFF/WOFF: compile-time LDS float offsets (buffer parity).
// SH: run previous step's bp extraction in the ds_read shadow.
#define STEP(ROFF, WOFF, SH)                                                   \
  {                                                                            \
    const float4* rp_ = (const float4*)(state_s + (ROFF) + g * SPAD);          \
    float4 a0 = rp_[0], a1 = rp_[1], a2 = rp_[2], a3 = rp_[3];                 \
    float potB = 0.f;                                                          \
    if (g0) potB = prow2[ccur];                                                \
    prow2 = (prow2 < prowLast) ? prow2 + CC : prow2;                           \
    if (SH) DO_BP                                                              \
    float t0 = a0.x + tr[0], t1 = a0.y + tr[1], t2 = a0.z + tr[2],             \
          t3 = a0.w + tr[3];                                                   \
    float t4 = a1.x + tr[4], t5 = a1.y + tr[5], t6 = a1.z + tr[6],             \
          t7 = a1.w + tr[7];                                                   \
    float t8 = a2.x + tr[8], t9 = a2.y + tr[9], tA = a2.z + tr[10],            \
          tB = a2.w + tr[11];                                                  \
    float tC = a3.x + tr[12], tD = a3.y + tr[13], tE = a3.z + tr[14],          \
          tF = a3.w + tr[15];                                                  \
    float m = fmaxf(F3(F3(t0, t1, t2), F3(t3, t4, t5), F3(t6, t7, t8)),        \
                    F3(F3(t9, tA, tB), F3(tC, tD, tE), tF));                   \
    m = dppmaxf<0xB1>(m);                                                      \
    m = dppmaxf<0x4E>(m);                                                      \
    m = dppmaxf<0x141>(m);                                                     \
    if (g0) *(state_s + (WOFF) + wslot) = m + pot;                             \
    pot = potA; potA = potB;                                                   \
    s0 = t0; s1 = t1; s2 = t2; s3 = t3; s4 = t4; s5 = t5; s6 = t6; s7 = t7;    \
    s8 = t8; s9 = t9; sA = tA; sB = tB; sC = tC; sD = tD; sE = tE; sF = tF;    \
    sm = m;                                                                    \
    asm volatile("s_waitcnt lgkmcnt(0)\n\ts_barrier" ::: "memory");            \
  }

__global__ __launch_bounds__(NTH, 1) void crf_viterbi(
    const float* __restrict__ inputs, const unsigned char* __restrict__ mask_bytes,
    const float* __restrict__ trans, float* __restrict__ out) {
  extern __shared__ unsigned char smem[];
  unsigned char* bp_s = smem;                  // [T-1][C] u8 backpointers
  float* state_s = (float*)(smem + BP_BYTES);  // [2][GR*SPAD] padded dbuf state
  int* wsum = (int*)(state_s + STATE_FLOATS);

  const int b = blockIdx.x;
  const int tid = threadIdx.x;
  const int lane = tid & 63;
  const int wave = tid >> 6;
  const int ccur = tid >> 3;  // 0..127
  const int g = tid & 7;      // cprev group (8 adjacent lanes per tag)
  const bool g0 = (g == 0);
  const unsigned gbase = (unsigned)(g * JP);
  const int wslot = (ccur >> 4) * SPAD + (ccur & 15);

  // mask dtype detection: int32 (byte1 of elem0 == 0) vs bool/int8
  const int w4 = (mask_bytes[1] == 0) ? 4 : 1;
  if (tid < TT) {
    int mb = mask_bytes[(size_t)(b * TT + tid) * (size_t)w4] != 0;
    unsigned long long bal = __ballot(mb);
    if (lane == 0) wsum[wave] = __popcll(bal);
  }

  // forward transition fragment in registers: tr[j] = trans[g*16+j][ccur]
  float tr[JP];
#pragma unroll
  for (int j = 0; j < JP; ++j) tr[j] = trans[(g * JP + j) * CC + ccur];

  const float* pin = inputs + (size_t)b * TT * CC;

  // init: state(0) = inputs[b,0,:] into buffer par=0
  if (tid < CC) state_s[(tid >> 4) * SPAD + (tid & 15)] = pin[tid];
  __syncthreads();

  int L = 0;
#pragma unroll
  for (int i = 0; i < 8; ++i) L += wsum[i];  // L in [256, 512]

  // 2-deep pot prefetch pipeline (writer lanes only); L >= 256 so rows 1..3 exist
  float pot = 0.f, potA = 0.f;
  if (g0) {
    pot = pin[CC + ccur];       // row 1
    potA = pin[2 * CC + ccur];  // row 2
  }
  const float* prow2 = pin + 3 * CC;                   // next prefetch row (t+2)
  const float* prowLast = pin + (size_t)(L - 1) * CC;  // clamp

  // shadow regs (previous step's t-values + cluster max)
  float s0, s1, s2, s3, s4, s5, s6, s7, s8, s9, sA, sB, sC, sD, sE, sF, sm;
  unsigned char* bpw = bp_s + ccur;  // bp row cursor (advances CC per DO_BP)

  // ---- forward DP ----
  STEP(0, GR * SPAD, 0);  // prime: t=1 (reads par0, writes par1, no shadow yet)
  int t = 2;
  for (; t + 1 < L; t += 2) {
    STEP(GR * SPAD, 0, 1);  // even t: read par1, write par0
    STEP(0, GR * SPAD, 1);  // odd t+1: read par0, write par1
  }
  if (t < L) {              // leftover single step (L odd): t = L-1, even
    STEP(GR * SPAD, 0, 1);
  }
  DO_BP  // flush last step's backpointers
  asm volatile("s_waitcnt lgkmcnt(0)\n\ts_barrier" ::: "memory");

  float* outv = out + OFF_VIT + b * TT;

  // --- epilogue: wave 0 = final argmax + backtrack; waves 1..15 = bulk copies ---
  if (wave == 0) {
    const float* fs = state_s + ((L - 1) & 1) * (GR * SPAD);
    float v1 = fs[(lane >> 4) * SPAD + (lane & 15)];
    int c2 = lane + 64;
    float v2 = fs[(c2 >> 4) * SPAD + (c2 & 15)];
    float v;
    int idx;
    if (v2 > v1) { v = v2; idx = c2; } else { v = v1; idx = lane; }
    bfly6(v, idx);

    // tags for t >= L-1 all equal last_tag (identity backpointers past length)
    for (int t2 = L - 1 + lane; t2 < TT; t2 += 64) outv[t2] = (float)idx;
    if (lane == 0) {
      out[OFF_LEN + b] = (float)L;
      int cur = idx;
      for (int tt = L - 2; tt >= 0; --tt) {
        cur = bp_s[tt * CC + cur];
        outv[tt] = (float)cur;
      }
    }
  } else {
    if (wave == 1) out[OFF_TR + b * 64 + lane] = trans[b * 64 + lane];
    const float4* src = (const float4*)pin;
    float4* dst = (float4*)(out + OFF_INP + (size_t)b * TT * CC);
    for (int i = tid - 64; i < TT * CC / 4; i += NTH - 64) dst[i] = src[i];
  }
}

extern "C" void kernel_launch(void* const* d_in, const int* in_sizes, int n_in,
                              void* d_out, int out_size, void* d_ws, size_t ws_size,
                              hipStream_t stream) {
  const float* inputs = (const float*)d_in[0];
  const unsigned char* mask = (const unsigned char*)d_in[1];
  const float* trans = (const float*)d_in[2];
  float* out = (float*)d_out;

  crf_viterbi<<<BB, NTH, SMEM_BYTES, stream>>>(inputs, mask, trans, out);
}